// Round 13
// baseline (188.649 us; speedup 1.0000x reference)
//
#include <hip/hip_runtime.h>
#include <hip/hip_bf16.h>
#include <stdint.h>

// B=16, S=512, D=512, H=8, DH=64. Float tensors fp32; mask int32; out fp32.
// Internals: bf16 MFMA operands, fp32 accumulation.

typedef __hip_bfloat16 bf16;
typedef __bf16 bf16x8 __attribute__((ext_vector_type(8)));
typedef float f32x4 __attribute__((ext_vector_type(4)));

#define MFMA16(a, b, c) __builtin_amdgcn_mfma_f32_16x16x32_bf16((a), (b), (c), 0, 0, 0)
// Compiler-only fence (r7-proven): stops LLVM hoisting same-wave cross-lane
// ds_reads above ds_writes; zero instructions, global loads stay in flight.
#define WAVE_LDS_FENCE() asm volatile("" ::: "memory")

static __device__ __forceinline__ bf16 f2b(float v) { return __float2bfloat16(v); }
static __device__ __forceinline__ bf16x8 ld8(const bf16* p) { return *(const bf16x8*)p; }
static __device__ __forceinline__ uint16_t f2bu(float v) {
  return __hip_bfloat16_raw(__float2bfloat16(v)).x;
}
static __device__ __forceinline__ float bu2f(uint32_t u) {
  union { uint32_t i; float f; } c;
  c.i = u << 16;
  return c.f;
}
// m97-style async global->LDS, 16 B/lane (HW: wave-uniform base + lane*16 —
// LDS layout is slot-fixed; we choose the SOURCE per slot, enabling the XOR
// swizzle below without breaking the DMA's lane-linear destination rule).
static __device__ __forceinline__ void stage16(const bf16* g, bf16* l) {
  __builtin_amdgcn_global_load_lds(
      (const __attribute__((address_space(1))) void*)g,
      (__attribute__((address_space(3))) void*)l, 16, 0, 0);
}

// ---------------------------------------------------------------- fused prep
// ln_rows (blocks 0..8191) + mask_pack (8192..24575) + weight transpose
// (24576..25599). Independent work fused to cut 2 dispatch bubbles.
__global__ __launch_bounds__(256) void prep(
    const float* __restrict__ x, const float* __restrict__ lng,
    const float* __restrict__ lnb, bf16* __restrict__ h,
    const int* __restrict__ mask, uint32_t* __restrict__ bits,
    const float* __restrict__ W0, const float* __restrict__ W1,
    const float* __restrict__ W2, const float* __restrict__ W3,
    bf16* __restrict__ T0, bf16* __restrict__ T1,
    bf16* __restrict__ T2, bf16* __restrict__ T3) {
  __shared__ float t[32][33];
  __shared__ float rs[4], rs2[4];
  const int bid = blockIdx.x;
  const int tid = threadIdx.x;

  if (bid < 8192) {  // -------- LayerNorm(x) -> h (bf16)
    int row = bid;
    const float* xr = x + (size_t)row * 512;
    float v0 = xr[tid], v1 = xr[tid + 256];
    float s = v0 + v1, s2 = v0 * v0 + v1 * v1;
#pragma unroll
    for (int m = 1; m < 64; m <<= 1) {
      s += __shfl_xor(s, m);
      s2 += __shfl_xor(s2, m);
    }
    int w = tid >> 6;
    if ((tid & 63) == 0) { rs[w] = s; rs2[w] = s2; }
    __syncthreads();
    s = rs[0] + rs[1] + rs[2] + rs[3];
    s2 = rs2[0] + rs2[1] + rs2[2] + rs2[3];
    float mean = s * (1.0f / 512.0f);
    float var = s2 * (1.0f / 512.0f) - mean * mean;
    float rstd = rsqrtf(var + 1e-5f);
    bf16* hr = h + (size_t)row * 512;
    hr[tid] = f2b((v0 - mean) * rstd * lng[tid] + lnb[tid]);
    hr[tid + 256] = f2b((v1 - mean) * rstd * lng[tid + 256] + lnb[tid + 256]);
  } else if (bid < 24576) {  // -------- mask -> bitmask (coalesced ballot)
    size_t e = (size_t)(bid - 8192) * 256 + tid;
    int mv = mask[e];
    unsigned long long bal = __ballot(mv != 0);
    if ((tid & 63) == 0) ((unsigned long long*)bits)[e >> 6] = bal;
  } else {  // -------- weight transpose + cast
    int tt = bid - 24576;                 // 0..1023
    int wsel = tt >> 8, rem = tt & 255;
    int n0 = (rem & 15) * 32, k0 = (rem >> 4) * 32;
    const float* src; bf16* dst;
    switch (wsel) {
      case 0: src = W0; dst = T0; break;
      case 1: src = W1; dst = T1; break;
      case 2: src = W2; dst = T2; break;
      default: src = W3; dst = T3; break;
    }
    int tx = tid & 31, ty = tid >> 5;     // 32 x 8
#pragma unroll
    for (int i = 0; i < 4; i++) {
      int kk = ty * 4 + i;
      t[kk][tx] = src[(k0 + kk) * 512 + n0 + tx];
    }
    __syncthreads();
#pragma unroll
    for (int i = 0; i < 4; i++) {
      int nn = ty * 4 + i;
      dst[(n0 + nn) * 512 + k0 + tx] = f2b(t[tx][nn]);
    }
  }
}

// ---------------------------------------------------------------- QKV GEMM v2
// BK=64 (8 chunks — half the barriers of r11) + XOR column-group swizzle:
// LDS slot (row, cg) holds global col-group (cg ^ (row&7)), so ds_read_b128
// fragment banks are perfectly spread (2-way = free; was ~8-way), while the
// staging source stays within the same 128 B row-line (coalescing kept).
__global__ __launch_bounds__(256) void gemm_qkv(
    const bf16* __restrict__ hm,
    const bf16* __restrict__ WT0, const bf16* __restrict__ WT1, const bf16* __restrict__ WT2,
    const float* __restrict__ bq, const float* __restrict__ bk, const float* __restrict__ bv,
    bf16* __restrict__ outq, bf16* __restrict__ outk, bf16* __restrict__ outvT) {
  const int sel = blockIdx.z;
  const bf16* WT = sel == 0 ? WT0 : (sel == 1 ? WT1 : WT2);
  const float* bias = sel == 0 ? bq : (sel == 1 ? bk : bv);
  __shared__ __align__(16) uint16_t SM[128 * 136];  // 34816 B; K-loop uses 32 KB
  bf16* As = (bf16*)SM;            // 128 x 64
  bf16* Bs = (bf16*)(SM + 8192);   // 128 x 64
  int tid = threadIdx.x;
  int w = tid >> 6, lane = tid & 63, q4 = lane >> 4, l16 = lane & 15;
  int wr = w >> 1, wc = w & 1;
  int m0 = blockIdx.x * 128, n0 = blockIdx.y * 128;
  f32x4 acc[4][4];
#pragma unroll
  for (int i = 0; i < 4; i++)
#pragma unroll
    for (int j = 0; j < 4; j++) acc[i][j] = (f32x4){0.f, 0.f, 0.f, 0.f};

  for (int kc = 0; kc < 8; kc++) {
    int k0 = kc * 64;
#pragma unroll
    for (int u0 = 0; u0 < 4; u0++) {
      int e = u0 * 256 + tid;            // 0..1023 ; slot = e*16B
      int row = e >> 3, cg = e & 7;
      int gcol = k0 + ((cg ^ (row & 7)) << 3);
      stage16(&hm[(size_t)(m0 + row) * 512 + gcol], &As[e * 8]);
      stage16(&WT[(size_t)(n0 + row) * 512 + gcol], &Bs[e * 8]);
    }
    __syncthreads();
#pragma unroll
    for (int ks = 0; ks < 2; ks++) {
      bf16x8 af[4], bfr[4];
#pragma unroll
      for (int rt = 0; rt < 4; rt++) {
        int row = wr * 64 + rt * 16 + l16;
        int cg = (ks * 4 + q4) ^ (l16 & 7);
        af[rt] = ld8(&As[row * 64 + cg * 8]);
      }
#pragma unroll
      for (int nt = 0; nt < 4; nt++) {
        int row = wc * 64 + nt * 16 + l16;
        int cg = (ks * 4 + q4) ^ (l16 & 7);
        bfr[nt] = ld8(&Bs[row * 64 + cg * 8]);
      }
#pragma unroll
      for (int rt = 0; rt < 4; rt++)
#pragma unroll
        for (int nt = 0; nt < 4; nt++) acc[rt][nt] = MFMA16(af[rt], bfr[nt], acc[rt][nt]);
    }
    __syncthreads();
  }

  if (sel != 2) {
    const float scale = sel == 0 ? 0.125f : 1.0f;
#pragma unroll
    for (int rt = 0; rt < 4; rt++)
#pragma unroll
      for (int nt = 0; nt < 4; nt++) {
        int ncol = wc * 64 + nt * 16 + l16;
        float bsv = bias[n0 + ncol];
#pragma unroll
        for (int r = 0; r < 4; r++) {
          int mrow = wr * 64 + rt * 16 + q4 * 4 + r;
          SM[mrow * 136 + ncol] = f2bu((acc[rt][nt][r] + bsv) * scale);
        }
      }
    __syncthreads();
    bf16* dst = sel == 0 ? outq : outk;
#pragma unroll
    for (int p = 0; p < 8; p++) {
      int e = p * 256 + tid;
      int row = e >> 4, c8 = (e & 15) * 8;
      bf16x8 vv = *(bf16x8*)&SM[row * 136 + c8];
      int gm = m0 + row, b_ = gm >> 9, s_ = gm & 511;
      int n = n0 + c8, hh = n >> 6, dh = n & 63;
      *(bf16x8*)(dst + ((size_t)((b_ * 8 + hh) * 512 + s_)) * 64 + dh) = vv;
    }
  } else {
#pragma unroll
    for (int rt = 0; rt < 4; rt++)
#pragma unroll
      for (int nt = 0; nt < 4; nt++) {
        int ncol = wc * 64 + nt * 16 + l16;
        float bsv = bias[n0 + ncol];
        union { uint16_t q[4]; uint2 u; } pk;
#pragma unroll
        for (int r = 0; r < 4; r++) pk.q[r] = f2bu(acc[rt][nt][r] + bsv);
        *(uint2*)&SM[ncol * 136 + wr * 64 + rt * 16 + q4 * 4] = pk.u;
      }
    __syncthreads();
#pragma unroll
    for (int p = 0; p < 8; p++) {
      int e = p * 256 + tid;
      int nn = e >> 4, s8 = (e & 15) * 8;
      bf16x8 vv = *(bf16x8*)&SM[nn * 136 + s8];
      int n = n0 + nn, hh = n >> 6, dh = n & 63;
      int gm = m0 + s8, b_ = gm >> 9, s_ = gm & 511;
      *(bf16x8*)(outvT + ((size_t)((b_ * 8 + hh) * 64 + dh)) * 512 + s_) = vv;
    }
  }
}

// ---------------------------------------------------------------- fused attention (r12 exact, 45.4 us)
__global__ __launch_bounds__(256, 2) void attn_fused(
    const bf16* __restrict__ q, const bf16* __restrict__ k, const bf16* __restrict__ vT,
    const uint32_t* __restrict__ bits, const float* __restrict__ lg,
    const float* __restrict__ lb, bf16* __restrict__ ctx) {
  const int id = blockIdx.x;              // 0..1023
  const int xcd = id & 7;
  const int j = id >> 3;                  // 0..127
  const int mt = j & 7;                   // 8 m-tiles of 64 rows
  const int bh = ((j >> 3) << 3) | xcd;   // bh%8 == xcd
  const int m0 = mt * 64;
  const int b = bh >> 3, hh = bh & 7;
  const int tid = threadIdx.x;
  const int w = tid >> 6, lane = tid & 63, q4 = lane >> 4, l16 = lane & 15;

  __shared__ uint16_t ST[512][66];              // raw scores (bf16 bits)
  __shared__ __align__(16) bf16 SB[2][2560];    // k/v staging
  __shared__ uint32_t GB[512];                  // {g,b} bf16-packed
  __shared__ float SMR[4][16][2];               // per-wave {mean,rstd}

  GB[tid] = (uint32_t)f2bu(lg[tid]) | ((uint32_t)f2bu(lb[tid]) << 16);
  GB[tid + 256] = (uint32_t)f2bu(lg[tid + 256]) | ((uint32_t)f2bu(lb[tid + 256]) << 16);

  const bf16* qb = q + ((size_t)bh * 512 + m0 + w * 16) * 64;
  const bf16* kb = k + (size_t)bh * 512 * 64;
  const bf16* vb = vT + (size_t)bh * 64 * 512;

  bf16x8 aq0 = ld8(qb + (size_t)l16 * 64 + q4 * 8);
  bf16x8 aq1 = ld8(qb + (size_t)l16 * 64 + 32 + q4 * 8);

  const int myrow = m0 + w * 16 + l16;
  uint32_t rbits[16];
#pragma unroll
  for (int c = 0; c < 16; c++)
    rbits[c] = bits[((size_t)b * 512 + myrow) * 16 + c];

  {
    int key0 = tid >> 3, dh8 = (tid & 7) * 8;
    *(bf16x8*)&SB[0][key0 * 72 + dh8] = ld8(kb + (size_t)key0 * 64 + dh8);
  }
  __syncthreads();

  float s[4] = {0.f, 0.f, 0.f, 0.f}, s2[4] = {0.f, 0.f, 0.f, 0.f};
  const int col = w * 16 + q4 * 4;
  for (int c = 0; c < 16; c++) {
    const int buf = c & 1;
    if (c < 15) {
      int key0 = tid >> 3, dh8 = (tid & 7) * 8;
      *(bf16x8*)&SB[buf ^ 1][key0 * 72 + dh8] =
          ld8(kb + (size_t)((c + 1) * 32 + key0) * 64 + dh8);
    }
#pragma unroll
    for (int kg = 0; kg < 2; kg++) {
      const bf16* kp = &SB[buf][(kg * 16 + l16) * 72];
      bf16x8 b0 = ld8(kp + q4 * 8);
      bf16x8 b1 = ld8(kp + 32 + q4 * 8);
      f32x4 acc = (f32x4){0.f, 0.f, 0.f, 0.f};
      acc = MFMA16(aq0, b0, acc);
      acc = MFMA16(aq1, b1, acc);
#pragma unroll
      for (int r = 0; r < 4; r++) {
        float v = acc[r];
        s[r] += v;
        s2[r] += v * v;
      }
      int key = c * 32 + kg * 16 + l16;
      *(uint32_t*)&ST[key][col] = (uint32_t)f2bu(acc[0]) | ((uint32_t)f2bu(acc[1]) << 16);
      *(uint32_t*)&ST[key][col + 2] = (uint32_t)f2bu(acc[2]) | ((uint32_t)f2bu(acc[3]) << 16);
    }
    __syncthreads();
  }

  float mean[4], rstd[4];
#pragma unroll
  for (int r = 0; r < 4; r++) {
    float a = s[r], a2 = s2[r];
#pragma unroll
    for (int mm = 1; mm < 16; mm <<= 1) {
      a += __shfl_xor(a, mm);
      a2 += __shfl_xor(a2, mm);
    }
    float mu = a * (1.0f / 512.0f);
    float var = a2 * (1.0f / 512.0f) - mu * mu;
    mean[r] = mu;
    rstd[r] = rsqrtf(var + 1e-5f);
  }
  if (l16 == 0) {
#pragma unroll
    for (int r = 0; r < 4; r++) {
      SMR[w][q4 * 4 + r][0] = mean[r];
      SMR[w][q4 * 4 + r][1] = rstd[r];
    }
  }
  WAVE_LDS_FENCE();
  const float mrow = SMR[w][l16][0];
  const float rrow = SMR[w][l16][1];

  {
    int dh = tid >> 2, kk8 = (tid & 3) * 8;
    *(bf16x8*)&SB[0][dh * 40 + kk8] = ld8(vb + (size_t)dh * 512 + kk8);
  }
  __syncthreads();

  f32x4 o[4];
#pragma unroll
  for (int nt = 0; nt < 4; nt++) o[nt] = (f32x4){0.f, 0.f, 0.f, 0.f};
  float se = 0.f;

#pragma unroll
  for (int c = 0; c < 16; c++) {
    const int buf = c & 1;
    if (c < 15) {
      int dh = tid >> 2, kk8 = (tid & 3) * 8;
      *(bf16x8*)&SB[buf ^ 1][dh * 40 + kk8] =
          ld8(vb + (size_t)dh * 512 + (c + 1) * 32 + kk8);
    }
    const uint32_t mb = rbits[c];
    union { uint16_t u[8]; bf16x8 v; } af;
#pragma unroll
    for (int jj = 0; jj < 8; jj++) {
      int key = c * 32 + q4 * 8 + jj;
      float sv = bu2f(ST[key][w * 16 + l16]);
      uint32_t gb = GB[key];
      float t = (sv - mrow) * rrow * bu2f(gb & 0xffffu) + bu2f(gb >> 16);
      t = ((mb >> (q4 * 8 + jj)) & 1u) ? t : -1.0e9f;
      float p = __expf(t);
      se += p;
      af.u[jj] = f2bu(p);
    }
#pragma unroll
    for (int nt = 0; nt < 4; nt++) {
      bf16x8 bv8 = ld8(&SB[buf][(nt * 16 + l16) * 40 + q4 * 8]);
      o[nt] = MFMA16(af.v, bv8, o[nt]);
    }
    __syncthreads();
  }

  se += __shfl_xor(se, 16);
  se += __shfl_xor(se, 32);
  float invr = 1.0f / se;
  float inv[4];
#pragma unroll
  for (int r = 0; r < 4; r++) inv[r] = __shfl(invr, q4 * 4 + r);

  bf16* cb = ctx + ((size_t)b * 512 + m0 + w * 16) * 512 + hh * 64;
#pragma unroll
  for (int nt = 0; nt < 4; nt++)
#pragma unroll
    for (int r = 0; r < 4; r++)
      cb[(size_t)(q4 * 4 + r) * 512 + nt * 16 + l16] = f2b(o[nt][r] * inv[r]);
}

// ---------------------------------------------------------------- out proj + residual (fp32 out)
// Same BK=64 + XOR swizzle as gemm_qkv.
__global__ __launch_bounds__(256) void gemm_out(
    const bf16* __restrict__ ctx, const bf16* __restrict__ WT,
    const float* __restrict__ bd, const float* __restrict__ x, float* __restrict__ out) {
  __shared__ __align__(16) bf16 As[128 * 64];
  __shared__ __align__(16) bf16 Bs[128 * 64];
  int tid = threadIdx.x;
  int w = tid >> 6, lane = tid & 63, q4 = lane >> 4, l16 = lane & 15;
  int wr = w >> 1, wc = w & 1;
  int m0 = blockIdx.x * 128, n0 = blockIdx.y * 128;
  f32x4 acc[4][4];
#pragma unroll
  for (int i = 0; i < 4; i++)
#pragma unroll
    for (int j = 0; j < 4; j++) acc[i][j] = (f32x4){0.f, 0.f, 0.f, 0.f};

  for (int kc = 0; kc < 8; kc++) {
    int k0 = kc * 64;
#pragma unroll
    for (int u0 = 0; u0 < 4; u0++) {
      int e = u0 * 256 + tid;
      int row = e >> 3, cg = e & 7;
      int gcol = k0 + ((cg ^ (row & 7)) << 3);
      stage16(&ctx[(size_t)(m0 + row) * 512 + gcol], &As[e * 8]);
      stage16(&WT[(size_t)(n0 + row) * 512 + gcol], &Bs[e * 8]);
    }
    __syncthreads();
#pragma unroll
    for (int ks = 0; ks < 2; ks++) {
      bf16x8 af[4], bfr[4];
#pragma unroll
      for (int rt = 0; rt < 4; rt++) {
        int row = wr * 64 + rt * 16 + l16;
        int cg = (ks * 4 + q4) ^ (l16 & 7);
        af[rt] = ld8(&As[row * 64 + cg * 8]);
      }
#pragma unroll
      for (int nt = 0; nt < 4; nt++) {
        int row = wc * 64 + nt * 16 + l16;
        int cg = (ks * 4 + q4) ^ (l16 & 7);
        bfr[nt] = ld8(&Bs[row * 64 + cg * 8]);
      }
#pragma unroll
      for (int rt = 0; rt < 4; rt++)
#pragma unroll
        for (int nt = 0; nt < 4; nt++) acc[rt][nt] = MFMA16(af[rt], bfr[nt], acc[rt][nt]);
    }
    __syncthreads();
  }
#pragma unroll
  for (int rt = 0; rt < 4; rt++) {
    int mbase = m0 + wr * 64 + rt * 16 + q4 * 4;
#pragma unroll
    for (int nt = 0; nt < 4; nt++) {
      int n = n0 + wc * 64 + nt * 16 + l16;
      float bsv = bd[n];
#pragma unroll
      for (int r = 0; r < 4; r++) {
        size_t idx = (size_t)(mbase + r) * 512 + n;
        out[idx] = acc[rt][nt][r] + bsv + x[idx];
      }
    }
  }
}

// ---------------------------------------------------------------- launch
extern "C" void kernel_launch(void* const* d_in, const int* in_sizes, int n_in,
                              void* d_out, int out_size, void* d_ws, size_t ws_size,
                              hipStream_t stream) {
  const float* x = (const float*)d_in[0];
  const int* mask = (const int*)d_in[1];
  const float* ln_g = (const float*)d_in[2];
  const float* ln_b = (const float*)d_in[3];
  const float* lna_g = (const float*)d_in[4];
  const float* lna_b = (const float*)d_in[5];
  const float* Wq = (const float*)d_in[6];
  const float* bq = (const float*)d_in[7];
  const float* Wk = (const float*)d_in[8];
  const float* bk = (const float*)d_in[9];
  const float* Wv = (const float*)d_in[10];
  const float* bv = (const float*)d_in[11];
  const float* Wd = (const float*)d_in[12];
  const float* bd = (const float*)d_in[13];

  char* ws = (char*)d_ws;
  const size_t MB = 1024 * 1024;
  if (ws_size < 44 * MB) return;
  bf16* h = (bf16*)(ws);                 // 8 MB  [8192,512]
  bf16* qd = (bf16*)(ws + 8 * MB);       // 8 MB  [B,H,S,DH]
  bf16* kd = (bf16*)(ws + 16 * MB);      // 8 MB  [B,H,S,DH]
  bf16* vTd = (bf16*)(ws + 24 * MB);     // 8 MB  [B,H,DH,S]
  bf16* ctx = (bf16*)(ws + 32 * MB);     // 8 MB  [B,S,D] bf16
  bf16* WqT = (bf16*)(ws + 40 * MB);
  bf16* WkT = (bf16*)(ws + 40 * MB + 512 * 1024);
  bf16* WvT = (bf16*)(ws + 40 * MB + 1024 * 1024);
  bf16* WdT = (bf16*)(ws + 40 * MB + 1536 * 1024);
  uint32_t* bits = (uint32_t*)(ws + 42 * MB);  // 512 KB

  prep<<<25600, 256, 0, stream>>>(x, ln_g, ln_b, h, mask, bits,
                                  Wq, Wk, Wv, Wd, WqT, WkT, WvT, WdT);
  gemm_qkv<<<dim3(64, 4, 3), 256, 0, stream>>>(h, WqT, WkT, WvT, bq, bk, bv, qd, kd, vTd);
  attn_fused<<<1024, 256, 0, stream>>>(qd, kd, vTd, bits, lna_g, lna_b, ctx);
  gemm_out<<<dim3(64, 4), 256, 0, stream>>>(ctx, WdT, bd, x, (float*)d_out);
}

// Round 14
// 179.233 us; speedup vs baseline: 1.0525x; 1.0525x over previous
//
#include <hip/hip_runtime.h>
#include <hip/hip_bf16.h>
#include <stdint.h>

// B=16, S=512, D=512, H=8, DH=64. Float tensors fp32; mask int32; out fp32.
// Internals: bf16 MFMA operands, fp32 accumulation.

typedef __hip_bfloat16 bf16;
typedef __bf16 bf16x8 __attribute__((ext_vector_type(8)));
typedef float f32x4 __attribute__((ext_vector_type(4)));

#define MFMA16(a, b, c) __builtin_amdgcn_mfma_f32_16x16x32_bf16((a), (b), (c), 0, 0, 0)
// Compiler-only fence (r7-proven): stops LLVM hoisting same-wave cross-lane
// ds_reads above ds_writes; zero instructions, global loads stay in flight.
#define WAVE_LDS_FENCE() asm volatile("" ::: "memory")

static __device__ __forceinline__ bf16 f2b(float v) { return __float2bfloat16(v); }
static __device__ __forceinline__ bf16x8 ld8(const bf16* p) { return *(const bf16x8*)p; }
static __device__ __forceinline__ uint16_t f2bu(float v) {
  return __hip_bfloat16_raw(__float2bfloat16(v)).x;
}
static __device__ __forceinline__ float bu2f(uint32_t u) {
  union { uint32_t i; float f; } c;
  c.i = u << 16;
  return c.f;
}
// m97-style async global->LDS, 16 B/lane (wave-uniform base + lane*16).
static __device__ __forceinline__ void stage16(const bf16* g, bf16* l) {
  __builtin_amdgcn_global_load_lds(
      (const __attribute__((address_space(1))) void*)g,
      (__attribute__((address_space(3))) void*)l, 16, 0, 0);
}

// ---------------------------------------------------------------- transpose + cast (r12)
__global__ __launch_bounds__(256) void transpose512(
    const float* __restrict__ W0, const float* __restrict__ W1,
    const float* __restrict__ W2, const float* __restrict__ W3,
    bf16* __restrict__ T0, bf16* __restrict__ T1,
    bf16* __restrict__ T2, bf16* __restrict__ T3) {
  __shared__ float t[32][33];
  const float* src; bf16* dst;
  switch (blockIdx.z) {
    case 0: src = W0; dst = T0; break;
    case 1: src = W1; dst = T1; break;
    case 2: src = W2; dst = T2; break;
    default: src = W3; dst = T3; break;
  }
  int tx = threadIdx.x, ty = threadIdx.y;  // 32 x 8
  int n0 = blockIdx.x * 32, k0 = blockIdx.y * 32;
#pragma unroll
  for (int i = 0; i < 4; i++) {
    int kk = ty * 4 + i;
    t[kk][tx] = src[(k0 + kk) * 512 + n0 + tx];
  }
  __syncthreads();
#pragma unroll
  for (int i = 0; i < 4; i++) {
    int nn = ty * 4 + i;
    dst[(n0 + nn) * 512 + k0 + tx] = f2b(t[tx][nn]);
  }
}

// ---------------------------------------------------------------- mask -> bitmask (r12)
__global__ __launch_bounds__(256) void mask_pack(const int* __restrict__ mask,
                                                 uint32_t* __restrict__ bits) {
  size_t t = (size_t)blockIdx.x * 256 + threadIdx.x;
  int mv = mask[t];
  unsigned long long bal = __ballot(mv != 0);
  if ((threadIdx.x & 63) == 0) {
    ((unsigned long long*)bits)[t >> 6] = bal;
  }
}

// ---------------------------------------------------------------- LayerNorm(x) -> h (r12)
__global__ __launch_bounds__(256) void ln_rows(
    const float* __restrict__ x, const float* __restrict__ g,
    const float* __restrict__ be, bf16* __restrict__ h) {
  int row = blockIdx.x;
  int tid = threadIdx.x;
  const float* xr = x + (size_t)row * 512;
  float v0 = xr[tid], v1 = xr[tid + 256];
  float s = v0 + v1, s2 = v0 * v0 + v1 * v1;
#pragma unroll
  for (int m = 1; m < 64; m <<= 1) {
    s += __shfl_xor(s, m);
    s2 += __shfl_xor(s2, m);
  }
  __shared__ float rs[4], rs2[4];
  int w = tid >> 6;
  if ((tid & 63) == 0) { rs[w] = s; rs2[w] = s2; }
  __syncthreads();
  s = rs[0] + rs[1] + rs[2] + rs[3];
  s2 = rs2[0] + rs2[1] + rs2[2] + rs2[3];
  float mean = s * (1.0f / 512.0f);
  float var = s2 * (1.0f / 512.0f) - mean * mean;
  float rstd = rsqrtf(var + 1e-5f);
  bf16* hr = h + (size_t)row * 512;
  hr[tid] = f2b((v0 - mean) * rstd * g[tid] + be[tid]);
  hr[tid + 256] = f2b((v1 - mean) * rstd * g[tid + 256] + be[tid + 256]);
}

// ---------------------------------------------------------------- QKV GEMM (r12 exact, BK=32)
__global__ __launch_bounds__(256) void gemm_qkv(
    const bf16* __restrict__ hm,
    const bf16* __restrict__ WT0, const bf16* __restrict__ WT1, const bf16* __restrict__ WT2,
    const float* __restrict__ bq, const float* __restrict__ bk, const float* __restrict__ bv,
    bf16* __restrict__ outq, bf16* __restrict__ outk, bf16* __restrict__ outvT) {
  const int sel = blockIdx.z;
  const bf16* WT = sel == 0 ? WT0 : (sel == 1 ? WT1 : WT2);
  const float* bias = sel == 0 ? bq : (sel == 1 ? bk : bv);
  __shared__ __align__(16) uint16_t SM[128 * 136];
  bf16* As = (bf16*)SM;
  bf16* Bs = (bf16*)(SM + 4096);
  int tid = threadIdx.x;
  int w = tid >> 6, lane = tid & 63, q4 = lane >> 4, l16 = lane & 15;
  int wr = w >> 1, wc = w & 1;
  int m0 = blockIdx.x * 128, n0 = blockIdx.y * 128;
  f32x4 acc[4][4];
#pragma unroll
  for (int i = 0; i < 4; i++)
#pragma unroll
    for (int j = 0; j < 4; j++) acc[i][j] = (f32x4){0.f, 0.f, 0.f, 0.f};

  for (int kc = 0; kc < 16; kc++) {
    int k0 = kc * 32;
#pragma unroll
    for (int u0 = 0; u0 < 2; u0++) {
      int e = u0 * 256 + tid;
      int row = e >> 2, c8 = (e & 3) * 8;
      stage16(&hm[(size_t)(m0 + row) * 512 + k0 + c8], &As[e * 8]);
      stage16(&WT[(size_t)(n0 + row) * 512 + k0 + c8], &Bs[e * 8]);
    }
    __syncthreads();
    bf16x8 af[4], bfr[4];
#pragma unroll
    for (int rt = 0; rt < 4; rt++)
      af[rt] = ld8(&As[(wr * 64 + rt * 16 + l16) * 32 + q4 * 8]);
#pragma unroll
    for (int nt = 0; nt < 4; nt++)
      bfr[nt] = ld8(&Bs[(wc * 64 + nt * 16 + l16) * 32 + q4 * 8]);
#pragma unroll
    for (int rt = 0; rt < 4; rt++)
#pragma unroll
      for (int nt = 0; nt < 4; nt++) acc[rt][nt] = MFMA16(af[rt], bfr[nt], acc[rt][nt]);
    __syncthreads();
  }

  if (sel != 2) {
    const float scale = sel == 0 ? 0.125f : 1.0f;
#pragma unroll
    for (int rt = 0; rt < 4; rt++)
#pragma unroll
      for (int nt = 0; nt < 4; nt++) {
        int ncol = wc * 64 + nt * 16 + l16;
        float bsv = bias[n0 + ncol];
#pragma unroll
        for (int r = 0; r < 4; r++) {
          int mrow = wr * 64 + rt * 16 + q4 * 4 + r;
          SM[mrow * 136 + ncol] = f2bu((acc[rt][nt][r] + bsv) * scale);
        }
      }
    __syncthreads();
    bf16* dst = sel == 0 ? outq : outk;
#pragma unroll
    for (int p = 0; p < 8; p++) {
      int e = p * 256 + tid;
      int row = e >> 4, c8 = (e & 15) * 8;
      bf16x8 vv = *(bf16x8*)&SM[row * 136 + c8];
      int gm = m0 + row, b_ = gm >> 9, s_ = gm & 511;
      int n = n0 + c8, hh = n >> 6, dh = n & 63;
      *(bf16x8*)(dst + ((size_t)((b_ * 8 + hh) * 512 + s_)) * 64 + dh) = vv;
    }
  } else {
#pragma unroll
    for (int rt = 0; rt < 4; rt++)
#pragma unroll
      for (int nt = 0; nt < 4; nt++) {
        int ncol = wc * 64 + nt * 16 + l16;
        float bsv = bias[n0 + ncol];
        union { uint16_t q[4]; uint2 u; } pk;
#pragma unroll
        for (int r = 0; r < 4; r++) pk.q[r] = f2bu(acc[rt][nt][r] + bsv);
        *(uint2*)&SM[ncol * 136 + wr * 64 + rt * 16 + q4 * 4] = pk.u;
      }
    __syncthreads();
#pragma unroll
    for (int p = 0; p < 8; p++) {
      int e = p * 256 + tid;
      int nn = e >> 4, s8 = (e & 15) * 8;
      bf16x8 vv = *(bf16x8*)&SM[nn * 136 + s8];
      int n = n0 + nn, hh = n >> 6, dh = n & 63;
      int gm = m0 + s8, b_ = gm >> 9, s_ = gm & 511;
      *(bf16x8*)(outvT + ((size_t)((b_ * 8 + hh) * 64 + dh)) * 512 + s_) = vv;
    }
  }
}

// ---------------------------------------------------------------- fused attention v11
// ST score buffer DELETED via recompute: phase 1 streams k chunks for LN
// stats only (registers); phase 3 re-stages k (L2-resident, cooperative LDS)
// + v, recomputes identical fp32 scores, applies LN+mask+exp in C-layout
// registers (mean/rstd already in the right lanes), transposes P through the
// per-wave PBT (r7-proven fence pattern), PV MFMA. LDS 80.4 KB -> ~30.5 KB
// => 4 blocks/CU resident (2x waves of r12). Mask bits from row-major `bits`
// staged once into padded sbits[64][17] (conflict-free broadcast reads).
__global__ __launch_bounds__(256, 4) void attn_fused(
    const bf16* __restrict__ q, const bf16* __restrict__ k, const bf16* __restrict__ vT,
    const uint32_t* __restrict__ bits, const float* __restrict__ lg,
    const float* __restrict__ lb, bf16* __restrict__ ctx) {
  const int id = blockIdx.x;              // 0..1023
  const int xcd = id & 7;
  const int j = id >> 3;                  // 0..127
  const int mt = j & 7;                   // 8 m-tiles of 64 rows
  const int bh = ((j >> 3) << 3) | xcd;   // bh%8 == xcd
  const int m0 = mt * 64;
  const int b = bh >> 3, hh = bh & 7;
  const int tid = threadIdx.x;
  const int w = tid >> 6, lane = tid & 63, q4 = lane >> 4, l16 = lane & 15;

  __shared__ __align__(16) bf16 SBk[2][32 * 72];   // 9216 B  k chunk
  __shared__ __align__(16) bf16 SBv[2][64 * 40];   // 10240 B v chunk
  __shared__ uint32_t GB[512];                     // 2048 B {gamma,beta} bf16-packed
  __shared__ uint32_t sbits[64][17];               // 4352 B mask bits (padded)
  __shared__ uint16_t PBT[4][32][18];              // 4608 B per-wave P transpose

  GB[tid] = (uint32_t)f2bu(lg[tid]) | ((uint32_t)f2bu(lb[tid]) << 16);
  GB[tid + 256] = (uint32_t)f2bu(lg[tid + 256]) | ((uint32_t)f2bu(lb[tid + 256]) << 16);
  {
    int row = tid >> 2, g = tid & 3;
    const uint32_t* src = bits + ((size_t)b * 512 + m0 + row) * 16 + g * 4;
    uint4 u = *(const uint4*)src;
    sbits[row][g * 4] = u.x; sbits[row][g * 4 + 1] = u.y;
    sbits[row][g * 4 + 2] = u.z; sbits[row][g * 4 + 3] = u.w;
  }

  const bf16* qb = q + ((size_t)bh * 512 + m0 + w * 16) * 64;
  const bf16* kb = k + (size_t)bh * 512 * 64;
  const bf16* vb = vT + (size_t)bh * 64 * 512;

  bf16x8 aq0 = ld8(qb + (size_t)l16 * 64 + q4 * 8);
  bf16x8 aq1 = ld8(qb + (size_t)l16 * 64 + 32 + q4 * 8);

  {
    int key0 = tid >> 3, dh8 = (tid & 7) * 8;
    *(bf16x8*)&SBk[0][key0 * 72 + dh8] = ld8(kb + (size_t)key0 * 64 + dh8);
  }
  __syncthreads();  // GB + sbits + k chunk 0

  // ---- phase 1: QK^T stats only (no storage)
  float s[4] = {0.f, 0.f, 0.f, 0.f}, s2[4] = {0.f, 0.f, 0.f, 0.f};
  for (int c = 0; c < 16; c++) {
    const int buf = c & 1;
    if (c < 15) {
      int key0 = tid >> 3, dh8 = (tid & 7) * 8;
      *(bf16x8*)&SBk[buf ^ 1][key0 * 72 + dh8] =
          ld8(kb + (size_t)((c + 1) * 32 + key0) * 64 + dh8);
    }
#pragma unroll
    for (int kg = 0; kg < 2; kg++) {
      const bf16* kp = &SBk[buf][(kg * 16 + l16) * 72];
      bf16x8 b0 = ld8(kp + q4 * 8);
      bf16x8 b1 = ld8(kp + 32 + q4 * 8);
      f32x4 acc = (f32x4){0.f, 0.f, 0.f, 0.f};
      acc = MFMA16(aq0, b0, acc);
      acc = MFMA16(aq1, b1, acc);
#pragma unroll
      for (int r = 0; r < 4; r++) {
        float v = acc[r];
        s[r] += v;
        s2[r] += v * v;
      }
    }
    __syncthreads();
  }

  float mean[4], rstd[4];
#pragma unroll
  for (int r = 0; r < 4; r++) {
    float a = s[r], a2 = s2[r];
#pragma unroll
    for (int mm = 1; mm < 16; mm <<= 1) {
      a += __shfl_xor(a, mm);
      a2 += __shfl_xor(a2, mm);
    }
    float mu = a * (1.0f / 512.0f);
    float var = a2 * (1.0f / 512.0f) - mu * mu;
    mean[r] = mu;
    rstd[r] = rsqrtf(var + 1e-5f);
  }

  // ---- phase 3: re-stage k + v, recompute scores, LN+mask+exp, PV
  {
    int key0 = tid >> 3, dh8 = (tid & 7) * 8;
    *(bf16x8*)&SBk[0][key0 * 72 + dh8] = ld8(kb + (size_t)key0 * 64 + dh8);
    int dh = tid >> 2, kk8 = (tid & 3) * 8;
    *(bf16x8*)&SBv[0][dh * 40 + kk8] = ld8(vb + (size_t)dh * 512 + kk8);
  }
  __syncthreads();

  f32x4 o[4];
#pragma unroll
  for (int nt = 0; nt < 4; nt++) o[nt] = (f32x4){0.f, 0.f, 0.f, 0.f};
  float se[4] = {0.f, 0.f, 0.f, 0.f};

  for (int c = 0; c < 16; c++) {
    const int buf = c & 1;
    if (c < 15) {
      int key0 = tid >> 3, dh8 = (tid & 7) * 8;
      *(bf16x8*)&SBk[buf ^ 1][key0 * 72 + dh8] =
          ld8(kb + (size_t)((c + 1) * 32 + key0) * 64 + dh8);
      int dh = tid >> 2, kk8 = (tid & 3) * 8;
      *(bf16x8*)&SBv[buf ^ 1][dh * 40 + kk8] =
          ld8(vb + (size_t)dh * 512 + (c + 1) * 32 + kk8);
    }
#pragma unroll
    for (int kg = 0; kg < 2; kg++) {
      const bf16* kp = &SBk[buf][(kg * 16 + l16) * 72];
      bf16x8 b0 = ld8(kp + q4 * 8);
      bf16x8 b1 = ld8(kp + 32 + q4 * 8);
      f32x4 acc = (f32x4){0.f, 0.f, 0.f, 0.f};
      acc = MFMA16(aq0, b0, acc);
      acc = MFMA16(aq1, b1, acc);
      uint32_t gb = GB[c * 32 + kg * 16 + l16];
      float gam = bu2f(gb & 0xffffu), bet = bu2f(gb >> 16);
      uint16_t p[4];
#pragma unroll
      for (int r = 0; r < 4; r++) {
        uint32_t dw = sbits[w * 16 + q4 * 4 + r][c];
        float t = (acc[r] - mean[r]) * rstd[r] * gam + bet;
        t = ((dw >> (kg * 16 + l16)) & 1u) ? t : -1.0e9f;
        float pf = __expf(t);
        se[r] += pf;
        p[r] = f2bu(pf);
      }
      *(uint32_t*)&PBT[w][kg * 16 + l16][q4 * 4] = (uint32_t)p[0] | ((uint32_t)p[1] << 16);
      *(uint32_t*)&PBT[w][kg * 16 + l16][q4 * 4 + 2] = (uint32_t)p[2] | ((uint32_t)p[3] << 16);
    }
    WAVE_LDS_FENCE();  // PBT writes -> cross-lane reads (r5 lesson)
    union { uint16_t u[8]; bf16x8 v; } af;
#pragma unroll
    for (int jj = 0; jj < 8; jj++) af.u[jj] = PBT[w][q4 * 8 + jj][l16];
    WAVE_LDS_FENCE();  // WAR vs next chunk's PBT writes
#pragma unroll
    for (int nt = 0; nt < 4; nt++) {
      bf16x8 bv8 = ld8(&SBv[buf][(nt * 16 + l16) * 40 + q4 * 8]);
      o[nt] = MFMA16(af.v, bv8, o[nt]);
    }
    __syncthreads();
  }

  float inv[4];
#pragma unroll
  for (int r = 0; r < 4; r++) {
    float a = se[r];
#pragma unroll
    for (int mm = 1; mm < 16; mm <<= 1) a += __shfl_xor(a, mm);
    inv[r] = 1.0f / a;
  }

  bf16* cb = ctx + ((size_t)b * 512 + m0 + w * 16) * 512 + hh * 64;
#pragma unroll
  for (int nt = 0; nt < 4; nt++)
#pragma unroll
    for (int r = 0; r < 4; r++)
      cb[(size_t)(q4 * 4 + r) * 512 + nt * 16 + l16] = f2b(o[nt][r] * inv[r]);
}

// ---------------------------------------------------------------- out proj + residual (r12 exact)
__global__ __launch_bounds__(256) void gemm_out(
    const bf16* __restrict__ ctx, const bf16* __restrict__ WT,
    const float* __restrict__ bd, const float* __restrict__ x, float* __restrict__ out) {
  __shared__ __align__(16) bf16 As[128 * 32];
  __shared__ __align__(16) bf16 Bs[128 * 32];
  int tid = threadIdx.x;
  int w = tid >> 6, lane = tid & 63, q4 = lane >> 4, l16 = lane & 15;
  int wr = w >> 1, wc = w & 1;
  int m0 = blockIdx.x * 128, n0 = blockIdx.y * 128;
  f32x4 acc[4][4];
#pragma unroll
  for (int i = 0; i < 4; i++)
#pragma unroll
    for (int j = 0; j < 4; j++) acc[i][j] = (f32x4){0.f, 0.f, 0.f, 0.f};

  for (int kc = 0; kc < 16; kc++) {
    int k0 = kc * 32;
#pragma unroll
    for (int u0 = 0; u0 < 2; u0++) {
      int e = u0 * 256 + tid;
      int row = e >> 2, c8 = (e & 3) * 8;
      stage16(&ctx[(size_t)(m0 + row) * 512 + k0 + c8], &As[e * 8]);
      stage16(&WT[(size_t)(n0 + row) * 512 + k0 + c8], &Bs[e * 8]);
    }
    __syncthreads();
    bf16x8 af[4], bfr[4];
#pragma unroll
    for (int rt = 0; rt < 4; rt++)
      af[rt] = ld8(&As[(wr * 64 + rt * 16 + l16) * 32 + q4 * 8]);
#pragma unroll
    for (int nt = 0; nt < 4; nt++)
      bfr[nt] = ld8(&Bs[(wc * 64 + nt * 16 + l16) * 32 + q4 * 8]);
#pragma unroll
    for (int rt = 0; rt < 4; rt++)
#pragma unroll
      for (int nt = 0; nt < 4; nt++) acc[rt][nt] = MFMA16(af[rt], bfr[nt], acc[rt][nt]);
    __syncthreads();
  }
#pragma unroll
  for (int rt = 0; rt < 4; rt++) {
    int mbase = m0 + wr * 64 + rt * 16 + q4 * 4;
#pragma unroll
    for (int nt = 0; nt < 4; nt++) {
      int n = n0 + wc * 64 + nt * 16 + l16;
      float bsv = bd[n];
#pragma unroll
      for (int r = 0; r < 4; r++) {
        size_t idx = (size_t)(mbase + r) * 512 + n;
        out[idx] = acc[rt][nt][r] + bsv + x[idx];
      }
    }
  }
}

// ---------------------------------------------------------------- launch
extern "C" void kernel_launch(void* const* d_in, const int* in_sizes, int n_in,
                              void* d_out, int out_size, void* d_ws, size_t ws_size,
                              hipStream_t stream) {
  const float* x = (const float*)d_in[0];
  const int* mask = (const int*)d_in[1];
  const float* ln_g = (const float*)d_in[2];
  const float* ln_b = (const float*)d_in[3];
  const float* lna_g = (const float*)d_in[4];
  const float* lna_b = (const float*)d_in[5];
  const float* Wq = (const float*)d_in[6];
  const float* bq = (const float*)d_in[7];
  const float* Wk = (const float*)d_in[8];
  const float* bk = (const float*)d_in[9];
  const float* Wv = (const float*)d_in[10];
  const float* bv = (const float*)d_in[11];
  const float* Wd = (const float*)d_in[12];
  const float* bd = (const float*)d_in[13];

  char* ws = (char*)d_ws;
  const size_t MB = 1024 * 1024;
  if (ws_size < 44 * MB) return;
  bf16* h = (bf16*)(ws);                 // 8 MB  [8192,512]
  bf16* qd = (bf16*)(ws + 8 * MB);       // 8 MB  [B,H,S,DH]
  bf16* kd = (bf16*)(ws + 16 * MB);      // 8 MB  [B,H,S,DH]
  bf16* vTd = (bf16*)(ws + 24 * MB);     // 8 MB  [B,H,DH,S]
  bf16* ctx = (bf16*)(ws + 32 * MB);     // 8 MB  [B,S,D] bf16
  bf16* WqT = (bf16*)(ws + 40 * MB);
  bf16* WkT = (bf16*)(ws + 40 * MB + 512 * 1024);
  bf16* WvT = (bf16*)(ws + 40 * MB + 1024 * 1024);
  bf16* WdT = (bf16*)(ws + 40 * MB + 1536 * 1024);
  uint32_t* bits = (uint32_t*)(ws + 42 * MB);  // 512 KB

  transpose512<<<dim3(16, 16, 4), dim3(32, 8), 0, stream>>>(Wq, Wk, Wv, Wd, WqT, WkT, WvT, WdT);
  mask_pack<<<16384, 256, 0, stream>>>(mask, bits);
  ln_rows<<<8192, 256, 0, stream>>>(x, ln_g, ln_b, h);
  gemm_qkv<<<dim3(64, 4, 3), 256, 0, stream>>>(h, WqT, WkT, WvT, bq, bk, bv, qd, kd, vTd);
  attn_fused<<<1024, 256, 0, stream>>>(qd, kd, vTd, bits, lna_g, lna_b, ctx);
  gemm_out<<<dim3(64, 4), 256, 0, stream>>>(ctx, WdT, bd, x, (float*)d_out);
}

// Round 15
// 179.071 us; speedup vs baseline: 1.0535x; 1.0009x over previous
//
#include <hip/hip_runtime.h>
#include <hip/hip_bf16.h>
#include <stdint.h>

// B=16, S=512, D=512, H=8, DH=64. Float tensors fp32; mask int32; out fp32.
// Internals: bf16 MFMA operands, fp32 accumulation.

typedef __hip_bfloat16 bf16;
typedef __bf16 bf16x8 __attribute__((ext_vector_type(8)));
typedef float f32x4 __attribute__((ext_vector_type(4)));

#define MFMA16(a, b, c) __builtin_amdgcn_mfma_f32_16x16x32_bf16((a), (b), (c), 0, 0, 0)

static __device__ __forceinline__ bf16 f2b(float v) { return __float2bfloat16(v); }
static __device__ __forceinline__ bf16x8 ld8(const bf16* p) { return *(const bf16x8*)p; }
static __device__ __forceinline__ uint16_t f2bu(float v) {
  return __hip_bfloat16_raw(__float2bfloat16(v)).x;
}
static __device__ __forceinline__ float bu2f(uint32_t u) {
  union { uint32_t i; float f; } c;
  c.i = u << 16;
  return c.f;
}
// m97-style async global->LDS, 16 B/lane (wave-uniform base + lane*16).
static __device__ __forceinline__ void stage16(const bf16* g, bf16* l) {
  __builtin_amdgcn_global_load_lds(
      (const __attribute__((address_space(1))) void*)g,
      (__attribute__((address_space(3))) void*)l, 16, 0, 0);
}

// ---------------------------------------------------------------- transpose + cast (r12)
__global__ __launch_bounds__(256) void transpose512(
    const float* __restrict__ W0, const float* __restrict__ W1,
    const float* __restrict__ W2, const float* __restrict__ W3,
    bf16* __restrict__ T0, bf16* __restrict__ T1,
    bf16* __restrict__ T2, bf16* __restrict__ T3) {
  __shared__ float t[32][33];
  const float* src; bf16* dst;
  switch (blockIdx.z) {
    case 0: src = W0; dst = T0; break;
    case 1: src = W1; dst = T1; break;
    case 2: src = W2; dst = T2; break;
    default: src = W3; dst = T3; break;
  }
  int tx = threadIdx.x, ty = threadIdx.y;  // 32 x 8
  int n0 = blockIdx.x * 32, k0 = blockIdx.y * 32;
#pragma unroll
  for (int i = 0; i < 4; i++) {
    int kk = ty * 4 + i;
    t[kk][tx] = src[(k0 + kk) * 512 + n0 + tx];
  }
  __syncthreads();
#pragma unroll
  for (int i = 0; i < 4; i++) {
    int nn = ty * 4 + i;
    dst[(n0 + nn) * 512 + k0 + tx] = f2b(t[tx][nn]);
  }
}

// ---------------------------------------------------------------- mask -> bitmask (r12)
__global__ __launch_bounds__(256) void mask_pack(const int* __restrict__ mask,
                                                 uint32_t* __restrict__ bits) {
  size_t t = (size_t)blockIdx.x * 256 + threadIdx.x;
  int mv = mask[t];
  unsigned long long bal = __ballot(mv != 0);
  if ((threadIdx.x & 63) == 0) {
    ((unsigned long long*)bits)[t >> 6] = bal;
  }
}

// ---------------------------------------------------------------- LayerNorm(x) -> h (r12)
__global__ __launch_bounds__(256) void ln_rows(
    const float* __restrict__ x, const float* __restrict__ g,
    const float* __restrict__ be, bf16* __restrict__ h) {
  int row = blockIdx.x;
  int tid = threadIdx.x;
  const float* xr = x + (size_t)row * 512;
  float v0 = xr[tid], v1 = xr[tid + 256];
  float s = v0 + v1, s2 = v0 * v0 + v1 * v1;
#pragma unroll
  for (int m = 1; m < 64; m <<= 1) {
    s += __shfl_xor(s, m);
    s2 += __shfl_xor(s2, m);
  }
  __shared__ float rs[4], rs2[4];
  int w = tid >> 6;
  if ((tid & 63) == 0) { rs[w] = s; rs2[w] = s2; }
  __syncthreads();
  s = rs[0] + rs[1] + rs[2] + rs[3];
  s2 = rs2[0] + rs2[1] + rs2[2] + rs2[3];
  float mean = s * (1.0f / 512.0f);
  float var = s2 * (1.0f / 512.0f) - mean * mean;
  float rstd = rsqrtf(var + 1e-5f);
  bf16* hr = h + (size_t)row * 512;
  hr[tid] = f2b((v0 - mean) * rstd * g[tid] + be[tid]);
  hr[tid + 256] = f2b((v1 - mean) * rstd * g[tid + 256] + be[tid + 256]);
}

// ---------------------------------------------------------------- QKV GEMM (r12 exact, BK=32)
__global__ __launch_bounds__(256) void gemm_qkv(
    const bf16* __restrict__ hm,
    const bf16* __restrict__ WT0, const bf16* __restrict__ WT1, const bf16* __restrict__ WT2,
    const float* __restrict__ bq, const float* __restrict__ bk, const float* __restrict__ bv,
    bf16* __restrict__ outq, bf16* __restrict__ outk, bf16* __restrict__ outvT) {
  const int sel = blockIdx.z;
  const bf16* WT = sel == 0 ? WT0 : (sel == 1 ? WT1 : WT2);
  const float* bias = sel == 0 ? bq : (sel == 1 ? bk : bv);
  __shared__ __align__(16) uint16_t SM[128 * 136];
  bf16* As = (bf16*)SM;
  bf16* Bs = (bf16*)(SM + 4096);
  int tid = threadIdx.x;
  int w = tid >> 6, lane = tid & 63, q4 = lane >> 4, l16 = lane & 15;
  int wr = w >> 1, wc = w & 1;
  int m0 = blockIdx.x * 128, n0 = blockIdx.y * 128;
  f32x4 acc[4][4];
#pragma unroll
  for (int i = 0; i < 4; i++)
#pragma unroll
    for (int j = 0; j < 4; j++) acc[i][j] = (f32x4){0.f, 0.f, 0.f, 0.f};

  for (int kc = 0; kc < 16; kc++) {
    int k0 = kc * 32;
#pragma unroll
    for (int u0 = 0; u0 < 2; u0++) {
      int e = u0 * 256 + tid;
      int row = e >> 2, c8 = (e & 3) * 8;
      stage16(&hm[(size_t)(m0 + row) * 512 + k0 + c8], &As[e * 8]);
      stage16(&WT[(size_t)(n0 + row) * 512 + k0 + c8], &Bs[e * 8]);
    }
    __syncthreads();
    bf16x8 af[4], bfr[4];
#pragma unroll
    for (int rt = 0; rt < 4; rt++)
      af[rt] = ld8(&As[(wr * 64 + rt * 16 + l16) * 32 + q4 * 8]);
#pragma unroll
    for (int nt = 0; nt < 4; nt++)
      bfr[nt] = ld8(&Bs[(wc * 64 + nt * 16 + l16) * 32 + q4 * 8]);
#pragma unroll
    for (int rt = 0; rt < 4; rt++)
#pragma unroll
      for (int nt = 0; nt < 4; nt++) acc[rt][nt] = MFMA16(af[rt], bfr[nt], acc[rt][nt]);
    __syncthreads();
  }

  if (sel != 2) {
    const float scale = sel == 0 ? 0.125f : 1.0f;
#pragma unroll
    for (int rt = 0; rt < 4; rt++)
#pragma unroll
      for (int nt = 0; nt < 4; nt++) {
        int ncol = wc * 64 + nt * 16 + l16;
        float bsv = bias[n0 + ncol];
#pragma unroll
        for (int r = 0; r < 4; r++) {
          int mrow = wr * 64 + rt * 16 + q4 * 4 + r;
          SM[mrow * 136 + ncol] = f2bu((acc[rt][nt][r] + bsv) * scale);
        }
      }
    __syncthreads();
    bf16* dst = sel == 0 ? outq : outk;
#pragma unroll
    for (int p = 0; p < 8; p++) {
      int e = p * 256 + tid;
      int row = e >> 4, c8 = (e & 15) * 8;
      bf16x8 vv = *(bf16x8*)&SM[row * 136 + c8];
      int gm = m0 + row, b_ = gm >> 9, s_ = gm & 511;
      int n = n0 + c8, hh = n >> 6, dh = n & 63;
      *(bf16x8*)(dst + ((size_t)((b_ * 8 + hh) * 512 + s_)) * 64 + dh) = vv;
    }
  } else {
#pragma unroll
    for (int rt = 0; rt < 4; rt++)
#pragma unroll
      for (int nt = 0; nt < 4; nt++) {
        int ncol = wc * 64 + nt * 16 + l16;
        float bsv = bias[n0 + ncol];
        union { uint16_t q[4]; uint2 u; } pk;
#pragma unroll
        for (int r = 0; r < 4; r++) pk.q[r] = f2bu(acc[rt][nt][r] + bsv);
        *(uint2*)&SM[ncol * 136 + wr * 64 + rt * 16 + q4 * 4] = pk.u;
      }
    __syncthreads();
#pragma unroll
    for (int p = 0; p < 8; p++) {
      int e = p * 256 + tid;
      int nn = e >> 4, s8 = (e & 15) * 8;
      bf16x8 vv = *(bf16x8*)&SM[nn * 136 + s8];
      int n = n0 + nn, hh = n >> 6, dh = n & 63;
      int gm = m0 + s8, b_ = gm >> 9, s_ = gm & 511;
      *(bf16x8*)(outvT + ((size_t)((b_ * 8 + hh) * 64 + dh)) * 512 + s_) = vv;
    }
  }
}

// ---------------------------------------------------------------- fused attention v12
// r14 recompute structure, but computes S^T (MFMA operand swap: A=k, B=q —
// both fragments are byte-identical loads). Each lane's C-regs then hold 4
// keys of ITS OWN q-row (l16): LN stats are per-lane scalars (2 shfl_xor),
// gamma/beta one ds_read_b128, mask dword a broadcast read, and the P->A
// transform is a fixed lane permutation done with 8 __shfl + 4 cndmask —
// the PBT LDS transpose (128 ds_read_u16/lane + fences, the r14 conflict
// source) is deleted. LDS 25.9 KB -> 4+ blocks/CU.
__global__ __launch_bounds__(256, 4) void attn_fused(
    const bf16* __restrict__ q, const bf16* __restrict__ k, const bf16* __restrict__ vT,
    const uint32_t* __restrict__ bits, const float* __restrict__ lg,
    const float* __restrict__ lb, bf16* __restrict__ ctx) {
  const int id = blockIdx.x;              // 0..1023
  const int xcd = id & 7;
  const int j = id >> 3;                  // 0..127
  const int mt = j & 7;                   // 8 m-tiles of 64 rows
  const int bh = ((j >> 3) << 3) | xcd;   // bh%8 == xcd
  const int m0 = mt * 64;
  const int b = bh >> 3, hh = bh & 7;
  const int tid = threadIdx.x;
  const int w = tid >> 6, lane = tid & 63, q4 = lane >> 4, l16 = lane & 15;

  __shared__ __align__(16) bf16 SBk[2][32 * 72];   // 9216 B  k chunk
  __shared__ __align__(16) bf16 SBv[2][64 * 40];   // 10240 B v chunk
  __shared__ uint32_t GB[512];                     // 2048 B {gamma,beta} bf16-packed
  __shared__ uint32_t sbits[64][17];               // 4352 B mask bits (padded)

  GB[tid] = (uint32_t)f2bu(lg[tid]) | ((uint32_t)f2bu(lb[tid]) << 16);
  GB[tid + 256] = (uint32_t)f2bu(lg[tid + 256]) | ((uint32_t)f2bu(lb[tid + 256]) << 16);
  {
    int row = tid >> 2, g = tid & 3;
    const uint32_t* src = bits + ((size_t)b * 512 + m0 + row) * 16 + g * 4;
    uint4 u = *(const uint4*)src;
    sbits[row][g * 4] = u.x; sbits[row][g * 4 + 1] = u.y;
    sbits[row][g * 4 + 2] = u.z; sbits[row][g * 4 + 3] = u.w;
  }

  const bf16* qb = q + ((size_t)bh * 512 + m0 + w * 16) * 64;
  const bf16* kb = k + (size_t)bh * 512 * 64;
  const bf16* vb = vT + (size_t)bh * 64 * 512;

  bf16x8 aq0 = ld8(qb + (size_t)l16 * 64 + q4 * 8);
  bf16x8 aq1 = ld8(qb + (size_t)l16 * 64 + 32 + q4 * 8);

  {
    int key0 = tid >> 3, dh8 = (tid & 7) * 8;
    *(bf16x8*)&SBk[0][key0 * 72 + dh8] = ld8(kb + (size_t)key0 * 64 + dh8);
  }
  __syncthreads();  // GB + sbits + k chunk 0

  // ---- phase 1: S^T stats only (per-lane row l16)
  float s = 0.f, s2 = 0.f;
  for (int c = 0; c < 16; c++) {
    const int buf = c & 1;
    if (c < 15) {
      int key0 = tid >> 3, dh8 = (tid & 7) * 8;
      *(bf16x8*)&SBk[buf ^ 1][key0 * 72 + dh8] =
          ld8(kb + (size_t)((c + 1) * 32 + key0) * 64 + dh8);
    }
#pragma unroll
    for (int kg = 0; kg < 2; kg++) {
      const bf16* kp = &SBk[buf][(kg * 16 + l16) * 72];
      bf16x8 b0 = ld8(kp + q4 * 8);
      bf16x8 b1 = ld8(kp + 32 + q4 * 8);
      f32x4 acc = (f32x4){0.f, 0.f, 0.f, 0.f};
      acc = MFMA16(b0, aq0, acc);   // A=k, B=q -> S^T[key][row]
      acc = MFMA16(b1, aq1, acc);
#pragma unroll
      for (int r = 0; r < 4; r++) {
        float v = acc[r];
        s += v;
        s2 += v * v;
      }
    }
    __syncthreads();
  }
  // combine the 4 q4 partials of row l16
  s += __shfl_xor(s, 16);  s += __shfl_xor(s, 32);
  s2 += __shfl_xor(s2, 16); s2 += __shfl_xor(s2, 32);
  const float mean = s * (1.0f / 512.0f);
  const float rstd = rsqrtf(s2 * (1.0f / 512.0f) - mean * mean + 1e-5f);

  // ---- phase 3: recompute S^T, LN+mask+exp in-lane, shuffle to A-layout, PV
  {
    int key0 = tid >> 3, dh8 = (tid & 7) * 8;
    *(bf16x8*)&SBk[0][key0 * 72 + dh8] = ld8(kb + (size_t)key0 * 64 + dh8);
    int dh = tid >> 2, kk8 = (tid & 3) * 8;
    *(bf16x8*)&SBv[0][dh * 40 + kk8] = ld8(vb + (size_t)dh * 512 + kk8);
  }
  __syncthreads();

  f32x4 o[4];
#pragma unroll
  for (int nt = 0; nt < 4; nt++) o[nt] = (f32x4){0.f, 0.f, 0.f, 0.f};
  float se = 0.f;
  const int src0 = ((q4 & 1) * 2) * 16 + l16;
  const int src1 = src0 + 16;
  const bool hi = (q4 >> 1) != 0;

  for (int c = 0; c < 16; c++) {
    const int buf = c & 1;
    if (c < 15) {
      int key0 = tid >> 3, dh8 = (tid & 7) * 8;
      *(bf16x8*)&SBk[buf ^ 1][key0 * 72 + dh8] =
          ld8(kb + (size_t)((c + 1) * 32 + key0) * 64 + dh8);
      int dh = tid >> 2, kk8 = (tid & 3) * 8;
      *(bf16x8*)&SBv[buf ^ 1][dh * 40 + kk8] =
          ld8(vb + (size_t)dh * 512 + (c + 1) * 32 + kk8);
    }
    const uint32_t dw = sbits[w * 16 + l16][c];  // broadcast across q4
    uint32_t Pk[2][2];
#pragma unroll
    for (int kg = 0; kg < 2; kg++) {
      const bf16* kp = &SBk[buf][(kg * 16 + l16) * 72];
      bf16x8 b0 = ld8(kp + q4 * 8);
      bf16x8 b1 = ld8(kp + 32 + q4 * 8);
      f32x4 acc = (f32x4){0.f, 0.f, 0.f, 0.f};
      acc = MFMA16(b0, aq0, acc);
      acc = MFMA16(b1, aq1, acc);
      uint4 gb4 = *(uint4*)&GB[c * 32 + kg * 16 + q4 * 4];  // 4 consecutive keys
      uint16_t p[4];
#pragma unroll
      for (int r = 0; r < 4; r++) {
        uint32_t gb = r == 0 ? gb4.x : (r == 1 ? gb4.y : (r == 2 ? gb4.z : gb4.w));
        float t = (acc[r] - mean) * rstd * bu2f(gb & 0xffffu) + bu2f(gb >> 16);
        t = ((dw >> (kg * 16 + q4 * 4 + r)) & 1u) ? t : -1.0e9f;
        float pf = __expf(t);
        se += pf;
        p[r] = f2bu(pf);
      }
      Pk[kg][0] = (uint32_t)p[0] | ((uint32_t)p[1] << 16);
      Pk[kg][1] = (uint32_t)p[2] | ((uint32_t)p[3] << 16);
    }
    // lane permutation: af dword t needs {P01,P23} of lanes src0/src1, group q4>>1
    uint32_t t00 = __shfl(Pk[0][0], src0), t01 = __shfl(Pk[1][0], src0);
    uint32_t t10 = __shfl(Pk[0][1], src0), t11 = __shfl(Pk[1][1], src0);
    uint32_t t20 = __shfl(Pk[0][0], src1), t21 = __shfl(Pk[1][0], src1);
    uint32_t t30 = __shfl(Pk[0][1], src1), t31 = __shfl(Pk[1][1], src1);
    union { uint32_t d[4]; bf16x8 v; } af;
    af.d[0] = hi ? t01 : t00;
    af.d[1] = hi ? t11 : t10;
    af.d[2] = hi ? t21 : t20;
    af.d[3] = hi ? t31 : t30;
#pragma unroll
    for (int nt = 0; nt < 4; nt++) {
      bf16x8 bv8 = ld8(&SBv[buf][(nt * 16 + l16) * 40 + q4 * 8]);
      o[nt] = MFMA16(af.v, bv8, o[nt]);
    }
    __syncthreads();
  }

  se += __shfl_xor(se, 16);
  se += __shfl_xor(se, 32);
  float invr = 1.0f / se;
  float inv[4];
#pragma unroll
  for (int r = 0; r < 4; r++) inv[r] = __shfl(invr, q4 * 4 + r);

  bf16* cb = ctx + ((size_t)b * 512 + m0 + w * 16) * 512 + hh * 64;
#pragma unroll
  for (int nt = 0; nt < 4; nt++)
#pragma unroll
    for (int r = 0; r < 4; r++)
      cb[(size_t)(q4 * 4 + r) * 512 + nt * 16 + l16] = f2b(o[nt][r] * inv[r]);
}

// ---------------------------------------------------------------- out proj + residual (r12 exact)
__global__ __launch_bounds__(256) void gemm_out(
    const bf16* __restrict__ ctx, const bf16* __restrict__ WT,
    const float* __restrict__ bd, const float* __restrict__ x, float* __restrict__ out) {
  __shared__ __align__(16) bf16 As[128 * 32];
  __shared__ __align__(16) bf16 Bs[128 * 32];
  int tid = threadIdx.x;
  int w = tid >> 6, lane = tid & 63, q4 = lane >> 4, l16 = lane & 15;
  int wr = w >> 1, wc = w & 1;
  int m0 = blockIdx.x * 128, n0 = blockIdx.y * 128;
  f32x4 acc[4][4];
#pragma unroll
  for (int i = 0; i < 4; i++)
#pragma unroll
    for (int j = 0; j < 4; j++) acc[i][j] = (f32x4){0.f, 0.f, 0.f, 0.f};

  for (int kc = 0; kc < 16; kc++) {
    int k0 = kc * 32;
#pragma unroll
    for (int u0 = 0; u0 < 2; u0++) {
      int e = u0 * 256 + tid;
      int row = e >> 2, c8 = (e & 3) * 8;
      stage16(&ctx[(size_t)(m0 + row) * 512 + k0 + c8], &As[e * 8]);
      stage16(&WT[(size_t)(n0 + row) * 512 + k0 + c8], &Bs[e * 8]);
    }
    __syncthreads();
    bf16x8 af[4], bfr[4];
#pragma unroll
    for (int rt = 0; rt < 4; rt++)
      af[rt] = ld8(&As[(wr * 64 + rt * 16 + l16) * 32 + q4 * 8]);
#pragma unroll
    for (int nt = 0; nt < 4; nt++)
      bfr[nt] = ld8(&Bs[(wc * 64 + nt * 16 + l16) * 32 + q4 * 8]);
#pragma unroll
    for (int rt = 0; rt < 4; rt++)
#pragma unroll
      for (int nt = 0; nt < 4; nt++) acc[rt][nt] = MFMA16(af[rt], bfr[nt], acc[rt][nt]);
    __syncthreads();
  }
#pragma unroll
  for (int rt = 0; rt < 4; rt++) {
    int mbase = m0 + wr * 64 + rt * 16 + q4 * 4;
#pragma unroll
    for (int nt = 0; nt < 4; nt++) {
      int n = n0 + wc * 64 + nt * 16 + l16;
      float bsv = bd[n];
#pragma unroll
      for (int r = 0; r < 4; r++) {
        size_t idx = (size_t)(mbase + r) * 512 + n;
        out[idx] = acc[rt][nt][r] + bsv + x[idx];
      }
    }
  }
}

// ---------------------------------------------------------------- launch
extern "C" void kernel_launch(void* const* d_in, const int* in_sizes, int n_in,
                              void* d_out, int out_size, void* d_ws, size_t ws_size,
                              hipStream_t stream) {
  const float* x = (const float*)d_in[0];
  const int* mask = (const int*)d_in[1];
  const float* ln_g = (const float*)d_in[2];
  const float* ln_b = (const float*)d_in[3];
  const float* lna_g = (const float*)d_in[4];
  const float* lna_b = (const float*)d_in[5];
  const float* Wq = (const float*)d_in[6];
  const float* bq = (const float*)d_in[7];
  const float* Wk = (const float*)d_in[8];
  const float* bk = (const float*)d_in[9];
  const float* Wv = (const float*)d_in[10];
  const float* bv = (const float*)d_in[11];
  const float* Wd = (const float*)d_in[12];
  const float* bd = (const float*)d_in[13];

  char* ws = (char*)d_ws;
  const size_t MB = 1024 * 1024;
  if (ws_size < 44 * MB) return;
  bf16* h = (bf16*)(ws);                 // 8 MB  [8192,512]
  bf16* qd = (bf16*)(ws + 8 * MB);       // 8 MB  [B,H,S,DH]
  bf16* kd = (bf16*)(ws + 16 * MB);      // 8 MB  [B,H,S,DH]
  bf16* vTd = (bf16*)(ws + 24 * MB);     // 8 MB  [B,H,DH,S]
  bf16* ctx = (bf16*)(ws + 32 * MB);     // 8 MB  [B,S,D] bf16
  bf16* WqT = (bf16*)(ws + 40 * MB);
  bf16* WkT = (bf16*)(ws + 40 * MB + 512 * 1024);
  bf16* WvT = (bf16*)(ws + 40 * MB + 1024 * 1024);
  bf16* WdT = (bf16*)(ws + 40 * MB + 1536 * 1024);
  uint32_t* bits = (uint32_t*)(ws + 42 * MB);  // 512 KB

  transpose512<<<dim3(16, 16, 4), dim3(32, 8), 0, stream>>>(Wq, Wk, Wv, Wd, WqT, WkT, WvT, WdT);
  mask_pack<<<16384, 256, 0, stream>>>(mask, bits);
  ln_rows<<<8192, 256, 0, stream>>>(x, ln_g, ln_b, h);
  gemm_qkv<<<dim3(64, 4, 3), 256, 0, stream>>>(h, WqT, WkT, WvT, bq, bk, bv, qd, kd, vTd);
  attn_fused<<<1024, 256, 0, stream>>>(qd, kd, vTd, bits, lna_g, lna_b, ctx);
  gemm_out<<<dim3(64, 4), 256, 0, stream>>>(ctx, WdT, bd, x, (float*)d_out);
}

// Round 16
// 177.831 us; speedup vs baseline: 1.0608x; 1.0070x over previous
//
#include <hip/hip_runtime.h>
#include <hip/hip_bf16.h>
#include <stdint.h>

// B=16, S=512, D=512, H=8, DH=64. Float tensors fp32; mask int32; out fp32.
// Internals: bf16 MFMA operands, fp32 accumulation.

typedef __hip_bfloat16 bf16;
typedef __bf16 bf16x8 __attribute__((ext_vector_type(8)));
typedef float f32x4 __attribute__((ext_vector_type(4)));

#define MFMA16(a, b, c) __builtin_amdgcn_mfma_f32_16x16x32_bf16((a), (b), (c), 0, 0, 0)

static __device__ __forceinline__ bf16 f2b(float v) { return __float2bfloat16(v); }
static __device__ __forceinline__ bf16x8 ld8(const bf16* p) { return *(const bf16x8*)p; }
static __device__ __forceinline__ uint16_t f2bu(float v) {
  return __hip_bfloat16_raw(__float2bfloat16(v)).x;
}
static __device__ __forceinline__ float bu2f(uint32_t u) {
  union { uint32_t i; float f; } c;
  c.i = u << 16;
  return c.f;
}
// m97-style async global->LDS, 16 B/lane (wave-uniform base + lane*16).
static __device__ __forceinline__ void stage16(const bf16* g, bf16* l) {
  __builtin_amdgcn_global_load_lds(
      (const __attribute__((address_space(1))) void*)g,
      (__attribute__((address_space(3))) void*)l, 16, 0, 0);
}

// ---------------------------------------------------------------- fused prep
// ln_rows (blocks 0..8191) + mask_pack (8192..24575) + weight transpose
// (24576..25599). Independent work fused to cut 2 dispatch bubbles.
__global__ __launch_bounds__(256) void prep(
    const float* __restrict__ x, const float* __restrict__ lng,
    const float* __restrict__ lnb, bf16* __restrict__ h,
    const int* __restrict__ mask, uint32_t* __restrict__ bits,
    const float* __restrict__ W0, const float* __restrict__ W1,
    const float* __restrict__ W2, const float* __restrict__ W3,
    bf16* __restrict__ T0, bf16* __restrict__ T1,
    bf16* __restrict__ T2, bf16* __restrict__ T3) {
  __shared__ float t[32][33];
  __shared__ float rs[4], rs2[4];
  const int bid = blockIdx.x;
  const int tid = threadIdx.x;

  if (bid < 8192) {  // -------- LayerNorm(x) -> h (bf16)
    int row = bid;
    const float* xr = x + (size_t)row * 512;
    float v0 = xr[tid], v1 = xr[tid + 256];
    float s = v0 + v1, s2 = v0 * v0 + v1 * v1;
#pragma unroll
    for (int m = 1; m < 64; m <<= 1) {
      s += __shfl_xor(s, m);
      s2 += __shfl_xor(s2, m);
    }
    int w = tid >> 6;
    if ((tid & 63) == 0) { rs[w] = s; rs2[w] = s2; }
    __syncthreads();
    s = rs[0] + rs[1] + rs[2] + rs[3];
    s2 = rs2[0] + rs2[1] + rs2[2] + rs2[3];
    float mean = s * (1.0f / 512.0f);
    float var = s2 * (1.0f / 512.0f) - mean * mean;
    float rstd = rsqrtf(var + 1e-5f);
    bf16* hr = h + (size_t)row * 512;
    hr[tid] = f2b((v0 - mean) * rstd * lng[tid] + lnb[tid]);
    hr[tid + 256] = f2b((v1 - mean) * rstd * lng[tid + 256] + lnb[tid + 256]);
  } else if (bid < 24576) {  // -------- mask -> bitmask (coalesced ballot)
    size_t e = (size_t)(bid - 8192) * 256 + tid;
    int mv = mask[e];
    unsigned long long bal = __ballot(mv != 0);
    if ((tid & 63) == 0) ((unsigned long long*)bits)[e >> 6] = bal;
  } else {  // -------- weight transpose + cast
    int tt = bid - 24576;                 // 0..1023
    int wsel = tt >> 8, rem = tt & 255;
    int n0 = (rem & 15) * 32, k0 = (rem >> 4) * 32;
    const float* src; bf16* dst;
    switch (wsel) {
      case 0: src = W0; dst = T0; break;
      case 1: src = W1; dst = T1; break;
      case 2: src = W2; dst = T2; break;
      default: src = W3; dst = T3; break;
    }
    int tx = tid & 31, ty = tid >> 5;     // 32 x 8
#pragma unroll
    for (int i = 0; i < 4; i++) {
      int kk = ty * 4 + i;
      t[kk][tx] = src[(k0 + kk) * 512 + n0 + tx];
    }
    __syncthreads();
#pragma unroll
    for (int i = 0; i < 4; i++) {
      int nn = ty * 4 + i;
      dst[(n0 + nn) * 512 + k0 + tx] = f2b(t[tx][nn]);
    }
  }
}

// ---------------------------------------------------------------- QKV GEMM (r12 exact, BK=32)
__global__ __launch_bounds__(256) void gemm_qkv(
    const bf16* __restrict__ hm,
    const bf16* __restrict__ WT0, const bf16* __restrict__ WT1, const bf16* __restrict__ WT2,
    const float* __restrict__ bq, const float* __restrict__ bk, const float* __restrict__ bv,
    bf16* __restrict__ outq, bf16* __restrict__ outk, bf16* __restrict__ outvT) {
  const int sel = blockIdx.z;
  const bf16* WT = sel == 0 ? WT0 : (sel == 1 ? WT1 : WT2);
  const float* bias = sel == 0 ? bq : (sel == 1 ? bk : bv);
  __shared__ __align__(16) uint16_t SM[128 * 136];
  bf16* As = (bf16*)SM;
  bf16* Bs = (bf16*)(SM + 4096);
  int tid = threadIdx.x;
  int w = tid >> 6, lane = tid & 63, q4 = lane >> 4, l16 = lane & 15;
  int wr = w >> 1, wc = w & 1;
  int m0 = blockIdx.x * 128, n0 = blockIdx.y * 128;
  f32x4 acc[4][4];
#pragma unroll
  for (int i = 0; i < 4; i++)
#pragma unroll
    for (int j = 0; j < 4; j++) acc[i][j] = (f32x4){0.f, 0.f, 0.f, 0.f};

  for (int kc = 0; kc < 16; kc++) {
    int k0 = kc * 32;
#pragma unroll
    for (int u0 = 0; u0 < 2; u0++) {
      int e = u0 * 256 + tid;
      int row = e >> 2, c8 = (e & 3) * 8;
      stage16(&hm[(size_t)(m0 + row) * 512 + k0 + c8], &As[e * 8]);
      stage16(&WT[(size_t)(n0 + row) * 512 + k0 + c8], &Bs[e * 8]);
    }
    __syncthreads();
    bf16x8 af[4], bfr[4];
#pragma unroll
    for (int rt = 0; rt < 4; rt++)
      af[rt] = ld8(&As[(wr * 64 + rt * 16 + l16) * 32 + q4 * 8]);
#pragma unroll
    for (int nt = 0; nt < 4; nt++)
      bfr[nt] = ld8(&Bs[(wc * 64 + nt * 16 + l16) * 32 + q4 * 8]);
#pragma unroll
    for (int rt = 0; rt < 4; rt++)
#pragma unroll
      for (int nt = 0; nt < 4; nt++) acc[rt][nt] = MFMA16(af[rt], bfr[nt], acc[rt][nt]);
    __syncthreads();
  }

  if (sel != 2) {
    const float scale = sel == 0 ? 0.125f : 1.0f;
#pragma unroll
    for (int rt = 0; rt < 4; rt++)
#pragma unroll
      for (int nt = 0; nt < 4; nt++) {
        int ncol = wc * 64 + nt * 16 + l16;
        float bsv = bias[n0 + ncol];
#pragma unroll
        for (int r = 0; r < 4; r++) {
          int mrow = wr * 64 + rt * 16 + q4 * 4 + r;
          SM[mrow * 136 + ncol] = f2bu((acc[rt][nt][r] + bsv) * scale);
        }
      }
    __syncthreads();
    bf16* dst = sel == 0 ? outq : outk;
#pragma unroll
    for (int p = 0; p < 8; p++) {
      int e = p * 256 + tid;
      int row = e >> 4, c8 = (e & 15) * 8;
      bf16x8 vv = *(bf16x8*)&SM[row * 136 + c8];
      int gm = m0 + row, b_ = gm >> 9, s_ = gm & 511;
      int n = n0 + c8, hh = n >> 6, dh = n & 63;
      *(bf16x8*)(dst + ((size_t)((b_ * 8 + hh) * 512 + s_)) * 64 + dh) = vv;
    }
  } else {
#pragma unroll
    for (int rt = 0; rt < 4; rt++)
#pragma unroll
      for (int nt = 0; nt < 4; nt++) {
        int ncol = wc * 64 + nt * 16 + l16;
        float bsv = bias[n0 + ncol];
        union { uint16_t q[4]; uint2 u; } pk;
#pragma unroll
        for (int r = 0; r < 4; r++) pk.q[r] = f2bu(acc[rt][nt][r] + bsv);
        *(uint2*)&SM[ncol * 136 + wr * 64 + rt * 16 + q4 * 4] = pk.u;
      }
    __syncthreads();
#pragma unroll
    for (int p = 0; p < 8; p++) {
      int e = p * 256 + tid;
      int nn = e >> 4, s8 = (e & 15) * 8;
      bf16x8 vv = *(bf16x8*)&SM[nn * 136 + s8];
      int n = n0 + nn, hh = n >> 6, dh = n & 63;
      int gm = m0 + s8, b_ = gm >> 9, s_ = gm & 511;
      *(bf16x8*)(outvT + ((size_t)((b_ * 8 + hh) * 64 + dh)) * 512 + s_) = vv;
    }
  }
}

// ---------------------------------------------------------------- fused attention (r15 exact)
// S^T via MFMA operand swap; per-lane LN stats; shuffle-based P->A transform.
__global__ __launch_bounds__(256, 4) void attn_fused(
    const bf16* __restrict__ q, const bf16* __restrict__ k, const bf16* __restrict__ vT,
    const uint32_t* __restrict__ bits, const float* __restrict__ lg,
    const float* __restrict__ lb, bf16* __restrict__ ctx) {
  const int id = blockIdx.x;              // 0..1023
  const int xcd = id & 7;
  const int j = id >> 3;                  // 0..127
  const int mt = j & 7;                   // 8 m-tiles of 64 rows
  const int bh = ((j >> 3) << 3) | xcd;   // bh%8 == xcd
  const int m0 = mt * 64;
  const int b = bh >> 3, hh = bh & 7;
  const int tid = threadIdx.x;
  const int w = tid >> 6, lane = tid & 63, q4 = lane >> 4, l16 = lane & 15;

  __shared__ __align__(16) bf16 SBk[2][32 * 72];   // 9216 B  k chunk
  __shared__ __align__(16) bf16 SBv[2][64 * 40];   // 10240 B v chunk
  __shared__ uint32_t GB[512];                     // 2048 B {gamma,beta} bf16-packed
  __shared__ uint32_t sbits[64][17];               // 4352 B mask bits (padded)

  GB[tid] = (uint32_t)f2bu(lg[tid]) | ((uint32_t)f2bu(lb[tid]) << 16);
  GB[tid + 256] = (uint32_t)f2bu(lg[tid + 256]) | ((uint32_t)f2bu(lb[tid + 256]) << 16);
  {
    int row = tid >> 2, g = tid & 3;
    const uint32_t* src = bits + ((size_t)b * 512 + m0 + row) * 16 + g * 4;
    uint4 u = *(const uint4*)src;
    sbits[row][g * 4] = u.x; sbits[row][g * 4 + 1] = u.y;
    sbits[row][g * 4 + 2] = u.z; sbits[row][g * 4 + 3] = u.w;
  }

  const bf16* qb = q + ((size_t)bh * 512 + m0 + w * 16) * 64;
  const bf16* kb = k + (size_t)bh * 512 * 64;
  const bf16* vb = vT + (size_t)bh * 64 * 512;

  bf16x8 aq0 = ld8(qb + (size_t)l16 * 64 + q4 * 8);
  bf16x8 aq1 = ld8(qb + (size_t)l16 * 64 + 32 + q4 * 8);

  {
    int key0 = tid >> 3, dh8 = (tid & 7) * 8;
    *(bf16x8*)&SBk[0][key0 * 72 + dh8] = ld8(kb + (size_t)key0 * 64 + dh8);
  }
  __syncthreads();  // GB + sbits + k chunk 0

  // ---- phase 1: S^T stats only (per-lane row l16)
  float s = 0.f, s2 = 0.f;
  for (int c = 0; c < 16; c++) {
    const int buf = c & 1;
    if (c < 15) {
      int key0 = tid >> 3, dh8 = (tid & 7) * 8;
      *(bf16x8*)&SBk[buf ^ 1][key0 * 72 + dh8] =
          ld8(kb + (size_t)((c + 1) * 32 + key0) * 64 + dh8);
    }
#pragma unroll
    for (int kg = 0; kg < 2; kg++) {
      const bf16* kp = &SBk[buf][(kg * 16 + l16) * 72];
      bf16x8 b0 = ld8(kp + q4 * 8);
      bf16x8 b1 = ld8(kp + 32 + q4 * 8);
      f32x4 acc = (f32x4){0.f, 0.f, 0.f, 0.f};
      acc = MFMA16(b0, aq0, acc);   // A=k, B=q -> S^T[key][row]
      acc = MFMA16(b1, aq1, acc);
#pragma unroll
      for (int r = 0; r < 4; r++) {
        float v = acc[r];
        s += v;
        s2 += v * v;
      }
    }
    __syncthreads();
  }
  s += __shfl_xor(s, 16);  s += __shfl_xor(s, 32);
  s2 += __shfl_xor(s2, 16); s2 += __shfl_xor(s2, 32);
  const float mean = s * (1.0f / 512.0f);
  const float rstd = rsqrtf(s2 * (1.0f / 512.0f) - mean * mean + 1e-5f);

  // ---- phase 3: recompute S^T, LN+mask+exp in-lane, shuffle to A-layout, PV
  {
    int key0 = tid >> 3, dh8 = (tid & 7) * 8;
    *(bf16x8*)&SBk[0][key0 * 72 + dh8] = ld8(kb + (size_t)key0 * 64 + dh8);
    int dh = tid >> 2, kk8 = (tid & 3) * 8;
    *(bf16x8*)&SBv[0][dh * 40 + kk8] = ld8(vb + (size_t)dh * 512 + kk8);
  }
  __syncthreads();

  f32x4 o[4];
#pragma unroll
  for (int nt = 0; nt < 4; nt++) o[nt] = (f32x4){0.f, 0.f, 0.f, 0.f};
  float se = 0.f;
  const int src0 = ((q4 & 1) * 2) * 16 + l16;
  const int src1 = src0 + 16;
  const bool hi = (q4 >> 1) != 0;

  for (int c = 0; c < 16; c++) {
    const int buf = c & 1;
    if (c < 15) {
      int key0 = tid >> 3, dh8 = (tid & 7) * 8;
      *(bf16x8*)&SBk[buf ^ 1][key0 * 72 + dh8] =
          ld8(kb + (size_t)((c + 1) * 32 + key0) * 64 + dh8);
      int dh = tid >> 2, kk8 = (tid & 3) * 8;
      *(bf16x8*)&SBv[buf ^ 1][dh * 40 + kk8] =
          ld8(vb + (size_t)dh * 512 + (c + 1) * 32 + kk8);
    }
    const uint32_t dw = sbits[w * 16 + l16][c];  // broadcast across q4
    uint32_t Pk[2][2];
#pragma unroll
    for (int kg = 0; kg < 2; kg++) {
      const bf16* kp = &SBk[buf][(kg * 16 + l16) * 72];
      bf16x8 b0 = ld8(kp + q4 * 8);
      bf16x8 b1 = ld8(kp + 32 + q4 * 8);
      f32x4 acc = (f32x4){0.f, 0.f, 0.f, 0.f};
      acc = MFMA16(b0, aq0, acc);
      acc = MFMA16(b1, aq1, acc);
      uint4 gb4 = *(uint4*)&GB[c * 32 + kg * 16 + q4 * 4];  // 4 consecutive keys
      uint16_t p[4];
#pragma unroll
      for (int r = 0; r < 4; r++) {
        uint32_t gb = r == 0 ? gb4.x : (r == 1 ? gb4.y : (r == 2 ? gb4.z : gb4.w));
        float t = (acc[r] - mean) * rstd * bu2f(gb & 0xffffu) + bu2f(gb >> 16);
        t = ((dw >> (kg * 16 + q4 * 4 + r)) & 1u) ? t : -1.0e9f;
        float pf = __expf(t);
        se += pf;
        p[r] = f2bu(pf);
      }
      Pk[kg][0] = (uint32_t)p[0] | ((uint32_t)p[1] << 16);
      Pk[kg][1] = (uint32_t)p[2] | ((uint32_t)p[3] << 16);
    }
    uint32_t t00 = __shfl(Pk[0][0], src0), t01 = __shfl(Pk[1][0], src0);
    uint32_t t10 = __shfl(Pk[0][1], src0), t11 = __shfl(Pk[1][1], src0);
    uint32_t t20 = __shfl(Pk[0][0], src1), t21 = __shfl(Pk[1][0], src1);
    uint32_t t30 = __shfl(Pk[0][1], src1), t31 = __shfl(Pk[1][1], src1);
    union { uint32_t d[4]; bf16x8 v; } af;
    af.d[0] = hi ? t01 : t00;
    af.d[1] = hi ? t11 : t10;
    af.d[2] = hi ? t21 : t20;
    af.d[3] = hi ? t31 : t30;
#pragma unroll
    for (int nt = 0; nt < 4; nt++) {
      bf16x8 bv8 = ld8(&SBv[buf][(nt * 16 + l16) * 40 + q4 * 8]);
      o[nt] = MFMA16(af.v, bv8, o[nt]);
    }
    __syncthreads();
  }

  se += __shfl_xor(se, 16);
  se += __shfl_xor(se, 32);
  float invr = 1.0f / se;
  float inv[4];
#pragma unroll
  for (int r = 0; r < 4; r++) inv[r] = __shfl(invr, q4 * 4 + r);

  bf16* cb = ctx + ((size_t)b * 512 + m0 + w * 16) * 512 + hh * 64;
#pragma unroll
  for (int nt = 0; nt < 4; nt++)
#pragma unroll
    for (int r = 0; r < 4; r++)
      cb[(size_t)(q4 * 4 + r) * 512 + nt * 16 + l16] = f2b(o[nt][r] * inv[r]);
}

// ---------------------------------------------------------------- out proj + residual (fp32 out)
// 64x128 tiles -> grid 512 = 2 blocks/CU (was 256 = 1/CU: every barrier
// exposed full staging latency with no cross-block overlap).
__global__ __launch_bounds__(256) void gemm_out(
    const bf16* __restrict__ ctx, const bf16* __restrict__ WT,
    const float* __restrict__ bd, const float* __restrict__ x, float* __restrict__ out) {
  __shared__ __align__(16) bf16 As[64 * 32];
  __shared__ __align__(16) bf16 Bs[128 * 32];
  int tid = threadIdx.x;
  int w = tid >> 6, lane = tid & 63, q4 = lane >> 4, l16 = lane & 15;
  int m0 = blockIdx.x * 64, n0 = blockIdx.y * 128;
  f32x4 acc[4][2];
#pragma unroll
  for (int i = 0; i < 4; i++)
#pragma unroll
    for (int j = 0; j < 2; j++) acc[i][j] = (f32x4){0.f, 0.f, 0.f, 0.f};

  for (int kc = 0; kc < 16; kc++) {
    int k0 = kc * 32;
    {
      int e = tid;                        // A: 64x32 = 256 units
      int row = e >> 2, c8 = (e & 3) * 8;
      stage16(&ctx[(size_t)(m0 + row) * 512 + k0 + c8], &As[e * 8]);
    }
#pragma unroll
    for (int u0 = 0; u0 < 2; u0++) {      // B: 128x32 = 512 units
      int e = u0 * 256 + tid;
      int row = e >> 2, c8 = (e & 3) * 8;
      stage16(&WT[(size_t)(n0 + row) * 512 + k0 + c8], &Bs[e * 8]);
    }
    __syncthreads();
    bf16x8 af[4], bfr[2];
#pragma unroll
    for (int rt = 0; rt < 4; rt++)
      af[rt] = ld8(&As[(rt * 16 + l16) * 32 + q4 * 8]);
#pragma unroll
    for (int nt = 0; nt < 2; nt++)
      bfr[nt] = ld8(&Bs[(w * 32 + nt * 16 + l16) * 32 + q4 * 8]);
#pragma unroll
    for (int rt = 0; rt < 4; rt++)
#pragma unroll
      for (int nt = 0; nt < 2; nt++) acc[rt][nt] = MFMA16(af[rt], bfr[nt], acc[rt][nt]);
    __syncthreads();
  }
#pragma unroll
  for (int rt = 0; rt < 4; rt++) {
    int mbase = m0 + rt * 16 + q4 * 4;
#pragma unroll
    for (int nt = 0; nt < 2; nt++) {
      int n = n0 + w * 32 + nt * 16 + l16;
      float bsv = bd[n];
#pragma unroll
      for (int r = 0; r < 4; r++) {
        size_t idx = (size_t)(mbase + r) * 512 + n;
        out[idx] = acc[rt][nt][r] + bsv + x[idx];
      }
    }
  }
}

// ---------------------------------------------------------------- launch
extern "C" void kernel_launch(void* const* d_in, const int* in_sizes, int n_in,
                              void* d_out, int out_size, void* d_ws, size_t ws_size,
                              hipStream_t stream) {
  const float* x = (const float*)d_in[0];
  const int* mask = (const int*)d_in[1];
  const float* ln_g = (const float*)d_in[2];
  const float* ln_b = (const float*)d_in[3];
  const float* lna_g = (const float*)d_in[4];
  const float* lna_b = (const float*)d_in[5];
  const float* Wq = (const float*)d_in[6];
  const float* bq = (const float*)d_in[7];
  const float* Wk = (const float*)d_in[8];
  const float* bk = (const float*)d_in[9];
  const float* Wv = (const float*)d_in[10];
  const float* bv = (const float*)d_in[11];
  const float* Wd = (const float*)d_in[12];
  const float* bd = (const float*)d_in[13];

  char* ws = (char*)d_ws;
  const size_t MB = 1024 * 1024;
  if (ws_size < 44 * MB) return;
  bf16* h = (bf16*)(ws);                 // 8 MB  [8192,512]
  bf16* qd = (bf16*)(ws + 8 * MB);       // 8 MB  [B,H,S,DH]
  bf16* kd = (bf16*)(ws + 16 * MB);      // 8 MB  [B,H,S,DH]
  bf16* vTd = (bf16*)(ws + 24 * MB);     // 8 MB  [B,H,DH,S]
  bf16* ctx = (bf16*)(ws + 32 * MB);     // 8 MB  [B,S,D] bf16
  bf16* WqT = (bf16*)(ws + 40 * MB);
  bf16* WkT = (bf16*)(ws + 40 * MB + 512 * 1024);
  bf16* WvT = (bf16*)(ws + 40 * MB + 1024 * 1024);
  bf16* WdT = (bf16*)(ws + 40 * MB + 1536 * 1024);
  uint32_t* bits = (uint32_t*)(ws + 42 * MB);  // 512 KB

  prep<<<25600, 256, 0, stream>>>(x, ln_g, ln_b, h, mask, bits,
                                  Wq, Wk, Wv, Wd, WqT, WkT, WvT, WdT);
  gemm_qkv<<<dim3(64, 4, 3), 256, 0, stream>>>(h, WqT, WkT, WvT, bq, bk, bv, qd, kd, vTd);
  attn_fused<<<1024, 256, 0, stream>>>(qd, kd, vTd, bits, lna_g, lna_b, ctx);
  gemm_out<<<dim3(128, 4), 256, 0, stream>>>(ctx, WdT, bd, x, (float*)d_out);
}